// Round 11
// baseline (359.221 us; speedup 1.0000x reference)
//
#include <hip/hip_runtime.h>
#include <stdint.h>

#define N_NODES 4096
#define K_NN    40
#define B_CLOUDS 8
#define F_IN    8
#define H_DIM   64
#define O_DIM   128

#define OUT_FEAT_ELEMS (B_CLOUDS * N_NODES * O_DIM)   // 4194304
#define EDGES          (B_CLOUDS * N_NODES * K_NN)    // 1310720

typedef short bf16x8 __attribute__((ext_vector_type(8)));
typedef float f32x4  __attribute__((ext_vector_type(4)));

__device__ __forceinline__ unsigned short f2bf(float f) {
    unsigned u = __float_as_uint(f);
    unsigned r = (u + 0x7FFFu + ((u >> 16) & 1u)) >> 16;   // RNE
    return (unsigned short)r;
}

// Launder a ballot result into SGPRs so the compiler can prove uniformity:
// the mask walk (ffs / and / popcount / branches) then lowers to SALU and
// co-issues with VALU instead of being done as per-lane 64-bit VALU math.
__device__ __forceinline__ unsigned long long uniform_mask(unsigned long long m) {
    unsigned lo = (unsigned)__builtin_amdgcn_readfirstlane((int)(unsigned)m);
    unsigned hi = (unsigned)__builtin_amdgcn_readfirstlane((int)(unsigned)(m >> 32));
    return (((unsigned long long)hi) << 32) | lo;
}

// ---------------------------------------------------------------------------
// Kernel A: exact KNN (bitwise-matching fp32 d2 + lax.top_k tie-break).
// 1024 threads = 16 waves = 16 targets per block; pos cloud SoA in 48 KB LDS.
// 2 blocks/CU -> 32 waves/CU. Same dataflow as R9/R10 (passing, absmax 512);
// only change: ballots laundered to SGPRs (scalarizes the insert-loop control).
// ---------------------------------------------------------------------------
__global__ __launch_bounds__(1024) void knn_kernel(const float* __restrict__ pos,
                                                   float* __restrict__ out)
{
    __shared__ float px[N_NODES];
    __shared__ float py[N_NODES];
    __shared__ float pz[N_NODES];

    const int b  = blockIdx.x >> 8;           // 256 blocks per cloud
    const int i0 = (blockIdx.x & 255) << 4;   // 16 targets per block
    const float* posb = pos + (size_t)b * N_NODES * 3;

    for (int t = threadIdx.x; t < N_NODES * 3; t += 1024) {
        float v = posb[t];
        int node = t / 3;
        int c = t - node * 3;
        if (c == 0) px[node] = v;
        else if (c == 1) py[node] = v;
        else pz[node] = v;
    }
    __syncthreads();

    const int wave = threadIdx.x >> 6;
    const int lane = threadIdx.x & 63;
    const int i = i0 + wave;
    const int ci = i >> 6;        // chunk containing self
    const int li = i & 63;        // lane of self within that chunk
    const int up_addr = ((lane + 1) & 63) << 2;   // ds_permute dest addr (hoisted)

    const float pix = px[i], piy = py[i], piz = pz[i];

    unsigned R = 0xFFFFFFFFu;   // sorted-ascending d2 bits across lanes
    unsigned P = 0xFFFFFFFFu;   // neighbor index payload

    for (int c = 0; c < 64; ++c) {
        const int j = (c << 6) | lane;
        // bitwise-exact fp32: ((dx*dx + dy*dy) + dz*dz), no FMA contraction
        float dx = __fsub_rn(pix, px[j]);
        float dy = __fsub_rn(piy, py[j]);
        float dz = __fsub_rn(piz, pz[j]);
        float d2 = __fadd_rn(__fadd_rn(__fmul_rn(dx, dx), __fmul_rn(dy, dy)),
                             __fmul_rn(dz, dz));
        unsigned d2b = __float_as_uint(d2);
        if (c == ci)                       // wave-uniform branch: 1 of 64 chunks
            d2b = (lane == li) ? 0xFFFFFFFFu : d2b;   // loop=False: no self

        const unsigned r39 = (unsigned)__builtin_amdgcn_readlane((int)R, 39);
        unsigned long long mask = uniform_mask(__ballot(d2b < r39));
        while (mask) {
            const int src = (int)__builtin_ctzll(mask);   // SALU (mask uniform)
            mask &= mask - 1;                             // SALU
            const unsigned kb = (unsigned)__builtin_amdgcn_readlane((int)d2b, src);
            const unsigned jj = (unsigned)((c << 6) | src);   // SALU
            const bool keep = (R <= kb);              // captured BEFORE updates
            unsigned long long le = uniform_mask(__ballot(keep));
            const int p = __builtin_popcount((unsigned)le)
                        + __builtin_popcount((unsigned)(le >> 32));   // SALU
            unsigned upR = (unsigned)__builtin_amdgcn_ds_permute(up_addr, (int)R);
            unsigned upP = (unsigned)__builtin_amdgcn_ds_permute(up_addr, (int)P);
            R = keep ? R : upR;
            P = keep ? P : upP;
            const bool at = (lane == p);              // one cmp, two cndmasks
            R = at ? kb : R;
            P = at ? jj : P;
        }
    }

    // Emit edges: src = global neighbor id, tgt = global target id (as floats)
    float* src_out = out + OUT_FEAT_ELEMS;
    float* tgt_out = src_out + EDGES;
    const int gi = b * N_NODES + i;
    if (lane < K_NN) {
        src_out[(size_t)gi * K_NN + lane] = (float)(b * N_NODES + (int)P);
        tgt_out[(size_t)gi * K_NN + lane] = (float)gi;
    }
}

// ---------------------------------------------------------------------------
// Kernel P: precompute W2 bf16 B-fragments into d_ws — UNCHANGED from R10.
// ---------------------------------------------------------------------------
__global__ __launch_bounds__(256) void w2prep_kernel(const float* __restrict__ W2,
                                                     unsigned short* __restrict__ ws)
{
    const int idx = blockIdx.x * 256 + threadIdx.x;   // 0..8191
    const int j    = idx & 7;
    const int lane = (idx >> 3) & 63;
    const int kt   = (idx >> 9) & 1;
    const int nt   = idx >> 10;
    const int k = kt * 32 + (lane >> 4) * 8 + j;
    const int n = nt * 16 + (lane & 15);
    ws[idx] = f2bf(W2[k * O_DIM + n]);
}

// ---------------------------------------------------------------------------
// Kernel B: per-edge MLP — UNCHANGED from R10 (4 blocks/CU, W2 frags in d_ws).
// ---------------------------------------------------------------------------
#define HSTR 72   // bf16 row stride for Hh: 144 B = 36 words -> 2-way bank (free)

__global__ __launch_bounds__(256, 4) void conv_kernel(
    const float* __restrict__ x, const float* __restrict__ pos,
    const float* __restrict__ W1, const float* __restrict__ b1,
    const unsigned short* __restrict__ w2f,   // d_ws B-fragments
    const float* __restrict__ b2,
    float* __restrict__ out)
{
    __shared__ __align__(16) unsigned short Hh[4][48 * HSTR];    // 27648 B
    __shared__ __align__(16) float msg[4][(K_NN + 1) * 12];      //  7872 B

    const int b    = blockIdx.x >> 10;
    const int i0   = (blockIdx.x & 1023) << 2;
    const int wave = threadIdx.x >> 6;
    const int lane = threadIdx.x & 63;
    const int quad = lane >> 4;
    const int col  = lane & 15;
    const int i    = i0 + wave;
    const int gi   = b * N_NODES + i;

    // ---- stage the 41 message rows [x_j(8) | rel(3) | pad] ----
    const float* src_edges = out + OUT_FEAT_ELEMS;
    if (lane <= K_NN) {
        int j;
        if (lane < K_NN) j = (int)src_edges[(size_t)gi * K_NN + lane] - b * N_NODES;
        else             j = i;   // self loop appended last
        const float* xr = x + ((size_t)b * N_NODES + j) * F_IN;
        float4 xa = *(const float4*)xr;
        float4 xb = *(const float4*)(xr + 4);
        const float* pj = pos + ((size_t)b * N_NODES + j) * 3;
        const float* pi = pos + ((size_t)b * N_NODES + i) * 3;
        float4 rel;
        rel.x = pj[0] - pi[0];
        rel.y = pj[1] - pi[1];
        rel.z = pj[2] - pi[2];
        rel.w = 0.0f;
        float* mrow = &msg[wave][lane * 12];
        *(float4*)(mrow)     = xa;
        *(float4*)(mrow + 4) = xb;
        *(float4*)(mrow + 8) = rel;
    }
    __syncthreads();

    // ---- phase 2: layer1 in fp32, lane = hidden channel; H -> LDS bf16 ----
    float w1r[11];
#pragma unroll
    for (int f = 0; f < 11; ++f) w1r[f] = W1[f * H_DIM + lane];
    const float b1r = b1[lane];

    unsigned short* Hw = Hh[wave];
    float h_last = 0.0f;
#pragma unroll 4
    for (int n = 0; n <= K_NN; ++n) {
        const float* mrow = &msg[wave][n * 12];
        float4 ma = *(const float4*)mrow;
        float4 mb = *(const float4*)(mrow + 4);
        float4 mc = *(const float4*)(mrow + 8);
        float h = b1r;
        h = fmaf(ma.x, w1r[0], h);  h = fmaf(ma.y, w1r[1], h);
        h = fmaf(ma.z, w1r[2], h);  h = fmaf(ma.w, w1r[3], h);
        h = fmaf(mb.x, w1r[4], h);  h = fmaf(mb.y, w1r[5], h);
        h = fmaf(mb.z, w1r[6], h);  h = fmaf(mb.w, w1r[7], h);
        h = fmaf(mc.x, w1r[8], h);  h = fmaf(mc.y, w1r[9], h);
        h = fmaf(mc.z, w1r[10], h);
        h = fmaxf(h, 0.0f);
        Hw[n * HSTR + lane] = f2bf(h);
        h_last = h;
    }
    // pad rows 41..47 with the self row (duplicates; max unchanged)
    {
        unsigned short hb = f2bf(h_last);
#pragma unroll
        for (int r = K_NN + 1; r < 48; ++r) Hw[r * HSTR + lane] = hb;
    }
    __syncthreads();

    // ---- phase 3: layer2 via MFMA. A frags from LDS; B frags from d_ws ----
    bf16x8 Af[3][2];
#pragma unroll
    for (int mt = 0; mt < 3; ++mt)
#pragma unroll
        for (int kt = 0; kt < 2; ++kt)
            Af[mt][kt] = *(const bf16x8*)&Hw[(mt * 16 + col) * HSTR + kt * 32 + quad * 8];

    const bf16x8* Bws = (const bf16x8*)w2f;
#pragma unroll
    for (int nt = 0; nt < 8; ++nt) {
        bf16x8 B0 = Bws[nt * 128 + lane];        // kt=0 frag (dwordx4, L1-hot)
        bf16x8 B1 = Bws[nt * 128 + 64 + lane];   // kt=1 frag

        f32x4 c0 = {0.f, 0.f, 0.f, 0.f};
        f32x4 c1 = {0.f, 0.f, 0.f, 0.f};
        f32x4 c2 = {0.f, 0.f, 0.f, 0.f};
        c0 = __builtin_amdgcn_mfma_f32_16x16x32_bf16(Af[0][0], B0, c0, 0, 0, 0);
        c1 = __builtin_amdgcn_mfma_f32_16x16x32_bf16(Af[1][0], B0, c1, 0, 0, 0);
        c2 = __builtin_amdgcn_mfma_f32_16x16x32_bf16(Af[2][0], B0, c2, 0, 0, 0);
        c0 = __builtin_amdgcn_mfma_f32_16x16x32_bf16(Af[0][1], B1, c0, 0, 0, 0);
        c1 = __builtin_amdgcn_mfma_f32_16x16x32_bf16(Af[1][1], B1, c1, 0, 0, 0);
        c2 = __builtin_amdgcn_mfma_f32_16x16x32_bf16(Af[2][1], B1, c2, 0, 0, 0);

        // max over all 48 rows (pads are duplicates): 12 regs, then cross-quad
        float vm = c0[0];
        vm = fmaxf(vm, c0[1]); vm = fmaxf(vm, c0[2]); vm = fmaxf(vm, c0[3]);
        vm = fmaxf(vm, c1[0]); vm = fmaxf(vm, c1[1]); vm = fmaxf(vm, c1[2]); vm = fmaxf(vm, c1[3]);
        vm = fmaxf(vm, c2[0]); vm = fmaxf(vm, c2[1]); vm = fmaxf(vm, c2[2]); vm = fmaxf(vm, c2[3]);
        vm = fmaxf(vm, __shfl_xor(vm, 16));
        vm = fmaxf(vm, __shfl_xor(vm, 32));
        vm += b2[nt * 16 + col];

        if (lane < 16) out[(size_t)gi * O_DIM + nt * 16 + lane] = vm;
    }
}

// ---------------------------------------------------------------------------
extern "C" void kernel_launch(void* const* d_in, const int* in_sizes, int n_in,
                              void* d_out, int out_size, void* d_ws, size_t ws_size,
                              hipStream_t stream) {
    const float* x   = (const float*)d_in[0];
    const float* pos = (const float*)d_in[1];
    const float* W1  = (const float*)d_in[2];
    const float* b1  = (const float*)d_in[3];
    const float* W2  = (const float*)d_in[4];
    const float* b2  = (const float*)d_in[5];
    float* out = (float*)d_out;
    unsigned short* w2f = (unsigned short*)d_ws;   // 8192 bf16 = 16 KB

    w2prep_kernel<<<32, 256, 0, stream>>>(W2, w2f);
    knn_kernel<<<(B_CLOUDS * N_NODES) / 16, 1024, 0, stream>>>(pos, out);
    conv_kernel<<<(B_CLOUDS * N_NODES) / 4, 256, 0, stream>>>(x, pos, W1, b1, w2f, b2, out);
}

// Round 12
// 355.026 us; speedup vs baseline: 1.0118x; 1.0118x over previous
//
#include <hip/hip_runtime.h>
#include <stdint.h>

#define N_NODES 4096
#define K_NN    40
#define B_CLOUDS 8
#define F_IN    8
#define H_DIM   64
#define O_DIM   128

#define OUT_FEAT_ELEMS (B_CLOUDS * N_NODES * O_DIM)   // 4194304
#define EDGES          (B_CLOUDS * N_NODES * K_NN)    // 1310720

typedef short bf16x8 __attribute__((ext_vector_type(8)));
typedef float f32x4  __attribute__((ext_vector_type(4)));

__device__ __forceinline__ unsigned short f2bf(float f) {
    unsigned u = __float_as_uint(f);
    unsigned r = (u + 0x7FFFu + ((u >> 16) & 1u)) >> 16;   // RNE
    return (unsigned short)r;
}

// ---------------------------------------------------------------------------
// Kernel A: exact KNN — EXACT REVERT to R10 (236 us, passing; R11's
// readfirstlane laundering regressed it: ballots were already uniform-SGPR).
// ---------------------------------------------------------------------------
__global__ __launch_bounds__(1024) void knn_kernel(const float* __restrict__ pos,
                                                   float* __restrict__ out)
{
    __shared__ float px[N_NODES];
    __shared__ float py[N_NODES];
    __shared__ float pz[N_NODES];

    const int b  = blockIdx.x >> 8;           // 256 blocks per cloud
    const int i0 = (blockIdx.x & 255) << 4;   // 16 targets per block
    const float* posb = pos + (size_t)b * N_NODES * 3;

    for (int t = threadIdx.x; t < N_NODES * 3; t += 1024) {
        float v = posb[t];
        int node = t / 3;
        int c = t - node * 3;
        if (c == 0) px[node] = v;
        else if (c == 1) py[node] = v;
        else pz[node] = v;
    }
    __syncthreads();

    const int wave = threadIdx.x >> 6;
    const int lane = threadIdx.x & 63;
    const int i = i0 + wave;
    const int ci = i >> 6;        // chunk containing self
    const int li = i & 63;        // lane of self within that chunk
    const int up_addr = ((lane + 1) & 63) << 2;   // ds_permute dest addr (hoisted)

    const float pix = px[i], piy = py[i], piz = pz[i];

    unsigned R = 0xFFFFFFFFu;   // sorted-ascending d2 bits across lanes
    unsigned P = 0xFFFFFFFFu;   // neighbor index payload

    for (int c = 0; c < 64; ++c) {
        const int j = (c << 6) | lane;
        // bitwise-exact fp32: ((dx*dx + dy*dy) + dz*dz), no FMA contraction
        float dx = __fsub_rn(pix, px[j]);
        float dy = __fsub_rn(piy, py[j]);
        float dz = __fsub_rn(piz, pz[j]);
        float d2 = __fadd_rn(__fadd_rn(__fmul_rn(dx, dx), __fmul_rn(dy, dy)),
                             __fmul_rn(dz, dz));
        unsigned d2b = __float_as_uint(d2);
        if (c == ci)                       // wave-uniform branch: 1 of 64 chunks
            d2b = (lane == li) ? 0xFFFFFFFFu : d2b;   // loop=False: no self

        const unsigned r39 = (unsigned)__builtin_amdgcn_readlane((int)R, 39);
        unsigned long long mask = __ballot(d2b < r39);
        while (mask) {
            const int src = (int)__builtin_ctzll(mask);
            mask &= mask - 1;
            const unsigned kb = (unsigned)__builtin_amdgcn_readlane((int)d2b, src);
            const unsigned jj = (unsigned)((c << 6) | src);           // SGPR
            const bool keep = (R <= kb);              // captured BEFORE updates
            unsigned long long le = __ballot(keep);
            const int p = (int)__builtin_popcountll(le);
            unsigned upR = (unsigned)__builtin_amdgcn_ds_permute(up_addr, (int)R);
            unsigned upP = (unsigned)__builtin_amdgcn_ds_permute(up_addr, (int)P);
            R = keep ? R : upR;
            P = keep ? P : upP;
            const bool at = (lane == p);              // one cmp, two cndmasks
            R = at ? kb : R;
            P = at ? jj : P;
        }
    }

    // Emit edges: src = global neighbor id, tgt = global target id (as floats)
    float* src_out = out + OUT_FEAT_ELEMS;
    float* tgt_out = src_out + EDGES;
    const int gi = b * N_NODES + i;
    if (lane < K_NN) {
        src_out[(size_t)gi * K_NN + lane] = (float)(b * N_NODES + (int)P);
        tgt_out[(size_t)gi * K_NN + lane] = (float)gi;
    }
}

// ---------------------------------------------------------------------------
// Kernel P: precompute W2 bf16 B-fragments into d_ws — UNCHANGED from R10.
// ---------------------------------------------------------------------------
__global__ __launch_bounds__(256) void w2prep_kernel(const float* __restrict__ W2,
                                                     unsigned short* __restrict__ ws)
{
    const int idx = blockIdx.x * 256 + threadIdx.x;   // 0..8191
    const int j    = idx & 7;
    const int lane = (idx >> 3) & 63;
    const int kt   = (idx >> 9) & 1;
    const int nt   = idx >> 10;
    const int k = kt * 32 + (lane >> 4) * 8 + j;
    const int n = nt * 16 + (lane & 15);
    ws[idx] = f2bf(W2[k * O_DIM + n]);
}

// ---------------------------------------------------------------------------
// Kernel B: per-edge MLP v3. No msg LDS: each lane gathers its own message
// row (lane n -> neighbor n; lanes 41-63 dup the self row), phase 2
// broadcasts lane n's registers via compile-time v_readlane (SGPR operands
// feed v_fma directly). LDS = Hh only (27.6 KB) -> 5 blocks/CU = 20 waves/CU,
// and the phase1->2 barrier disappears. Layer2 (64->128) bf16 MFMA with W2
// B-fragments from d_ws (L1-hot), unchanged from R10.
// ---------------------------------------------------------------------------
#define HSTR 72   // bf16 row stride for Hh: 144 B -> 16B-aligned rows, 2-way bank

__global__ __launch_bounds__(256, 5) void conv_kernel(
    const float* __restrict__ x, const float* __restrict__ pos,
    const float* __restrict__ W1, const float* __restrict__ b1,
    const unsigned short* __restrict__ w2f,   // d_ws B-fragments
    const float* __restrict__ b2,
    float* __restrict__ out)
{
    __shared__ __align__(16) unsigned short Hh[4][48 * HSTR];    // 27648 B

    const int b    = blockIdx.x >> 10;
    const int i0   = (blockIdx.x & 1023) << 2;
    const int wave = threadIdx.x >> 6;
    const int lane = threadIdx.x & 63;
    const int quad = lane >> 4;
    const int col  = lane & 15;
    const int i    = i0 + wave;
    const int gi   = b * N_NODES + i;

    // ---- per-lane gather: lane n holds message row n = [x_j(8) | rel(3)] ----
    const float* src_edges = out + OUT_FEAT_ELEMS;
    int j;
    if (lane < K_NN) j = (int)src_edges[(size_t)gi * K_NN + lane] - b * N_NODES;
    else             j = i;   // lane 40 = self loop row; 41-63 harmless dups
    const float* xr = x + ((size_t)b * N_NODES + j) * F_IN;
    float4 xa = *(const float4*)xr;
    float4 xb = *(const float4*)(xr + 4);
    const float* pj = pos + ((size_t)b * N_NODES + j) * 3;
    const float* pi = pos + ((size_t)b * N_NODES + i) * 3;
    float row[11];
    row[0] = xa.x; row[1] = xa.y; row[2] = xa.z; row[3] = xa.w;
    row[4] = xb.x; row[5] = xb.y; row[6] = xb.z; row[7] = xb.w;
    row[8]  = pj[0] - pi[0];
    row[9]  = pj[1] - pi[1];
    row[10] = pj[2] - pi[2];

    // ---- layer-1 weights: lane = hidden channel ----
    float w1r[11];
#pragma unroll
    for (int f = 0; f < 11; ++f) w1r[f] = W1[f * H_DIM + lane];
    const float b1r = b1[lane];

    // ---- phase 2: per neighbor-row n, broadcast row regs from lane n ----
    unsigned short* Hw = Hh[wave];
    float h = 0.0f;
#pragma unroll
    for (int n = 0; n <= K_NN; ++n) {
        h = b1r;
#pragma unroll
        for (int f = 0; f < 11; ++f) {
            float mv = __uint_as_float(
                (unsigned)__builtin_amdgcn_readlane((int)__float_as_uint(row[f]), n));
            h = fmaf(mv, w1r[f], h);
        }
        h = fmaxf(h, 0.0f);
        Hw[n * HSTR + lane] = f2bf(h);
    }
    // pad rows 41..47 with the self row (h still holds n=40 = self; max-safe)
    {
        unsigned short hb = f2bf(h);
#pragma unroll
        for (int r = K_NN + 1; r < 48; ++r) Hw[r * HSTR + lane] = hb;
    }
    __syncthreads();   // Hh is per-wave but keep cross-phase ordering airtight

    // ---- phase 3: layer2 via MFMA. A frags from LDS; B frags from d_ws ----
    bf16x8 Af[3][2];
#pragma unroll
    for (int mt = 0; mt < 3; ++mt)
#pragma unroll
        for (int kt = 0; kt < 2; ++kt)
            Af[mt][kt] = *(const bf16x8*)&Hw[(mt * 16 + col) * HSTR + kt * 32 + quad * 8];

    const bf16x8* Bws = (const bf16x8*)w2f;
#pragma unroll
    for (int nt = 0; nt < 8; ++nt) {
        bf16x8 B0 = Bws[nt * 128 + lane];        // kt=0 frag (dwordx4, L1-hot)
        bf16x8 B1 = Bws[nt * 128 + 64 + lane];   // kt=1 frag

        f32x4 c0 = {0.f, 0.f, 0.f, 0.f};
        f32x4 c1 = {0.f, 0.f, 0.f, 0.f};
        f32x4 c2 = {0.f, 0.f, 0.f, 0.f};
        c0 = __builtin_amdgcn_mfma_f32_16x16x32_bf16(Af[0][0], B0, c0, 0, 0, 0);
        c1 = __builtin_amdgcn_mfma_f32_16x16x32_bf16(Af[1][0], B0, c1, 0, 0, 0);
        c2 = __builtin_amdgcn_mfma_f32_16x16x32_bf16(Af[2][0], B0, c2, 0, 0, 0);
        c0 = __builtin_amdgcn_mfma_f32_16x16x32_bf16(Af[0][1], B1, c0, 0, 0, 0);
        c1 = __builtin_amdgcn_mfma_f32_16x16x32_bf16(Af[1][1], B1, c1, 0, 0, 0);
        c2 = __builtin_amdgcn_mfma_f32_16x16x32_bf16(Af[2][1], B1, c2, 0, 0, 0);

        // max over all 48 rows (pads are duplicates): 12 regs, then cross-quad
        float vm = c0[0];
        vm = fmaxf(vm, c0[1]); vm = fmaxf(vm, c0[2]); vm = fmaxf(vm, c0[3]);
        vm = fmaxf(vm, c1[0]); vm = fmaxf(vm, c1[1]); vm = fmaxf(vm, c1[2]); vm = fmaxf(vm, c1[3]);
        vm = fmaxf(vm, c2[0]); vm = fmaxf(vm, c2[1]); vm = fmaxf(vm, c2[2]); vm = fmaxf(vm, c2[3]);
        vm = fmaxf(vm, __shfl_xor(vm, 16));
        vm = fmaxf(vm, __shfl_xor(vm, 32));
        vm += b2[nt * 16 + col];

        if (lane < 16) out[(size_t)gi * O_DIM + nt * 16 + lane] = vm;
    }
}

// ---------------------------------------------------------------------------
extern "C" void kernel_launch(void* const* d_in, const int* in_sizes, int n_in,
                              void* d_out, int out_size, void* d_ws, size_t ws_size,
                              hipStream_t stream) {
    const float* x   = (const float*)d_in[0];
    const float* pos = (const float*)d_in[1];
    const float* W1  = (const float*)d_in[2];
    const float* b1  = (const float*)d_in[3];
    const float* W2  = (const float*)d_in[4];
    const float* b2  = (const float*)d_in[5];
    float* out = (float*)d_out;
    unsigned short* w2f = (unsigned short*)d_ws;   // 8192 bf16 = 16 KB

    w2prep_kernel<<<32, 256, 0, stream>>>(W2, w2f);
    knn_kernel<<<(B_CLOUDS * N_NODES) / 16, 1024, 0, stream>>>(pos, out);
    conv_kernel<<<(B_CLOUDS * N_NODES) / 4, 256, 0, stream>>>(x, pos, W1, b1, w2f, b2, out);
}